// Round 2
// baseline (390.602 us; speedup 1.0000x reference)
//
#include <hip/hip_runtime.h>

#define B_TOTAL 32768
#define NATOM   512
#define MDIM    64
#define KS      5

// ---------------------------------------------------------------------------
// K_PREP: fused perm (blocks 0..511) + gram (blocks 512..1023).
// ---------------------------------------------------------------------------
__global__ void k_prep(const float* __restrict__ ze, float* __restrict__ dT,
                       const float* __restrict__ D, float* __restrict__ G,
                       float* __restrict__ acc) {
    __shared__ float lds[64][65];
    const int t = threadIdx.x;
    if (blockIdx.x < 512) {
        const int n   = blockIdx.x >> 4;
        const int hw0 = (blockIdx.x & 15) * 64;
#pragma unroll
        for (int r = 0; r < 16; ++r) {
            int id = r * 256 + t;
            int c = id >> 6, i = id & 63;
            lds[c][i] = ze[n * 65536 + c * 1024 + hw0 + i];
        }
        __syncthreads();
#pragma unroll
        for (int r = 0; r < 16; ++r) {
            int id = r * 256 + t;
            int c = id & 63, j = id >> 6;
            int hw = hw0 + j;
            int h = hw >> 5, w = hw & 31;
            int m = (n << 1) | (h >> 4);
            int b = ((h & 15) << 11) | (w << 6) | c;
            dT[m * 32768 + b] = lds[c][j];
        }
    } else {
        const int i = blockIdx.x - 512;
        float* col = &lds[0][0];
        if (t < MDIM) col[t] = D[t * NATOM + i];
        __syncthreads();
        for (int j = t; j < NATOM; j += 256) {
            float s = 0.f;
#pragma unroll
            for (int m = 0; m < MDIM; ++m) s = fmaf(col[m], D[m * NATOM + j], s);
            G[i * NATOM + j] = s;
        }
        if (i == 0 && t == 0) *acc = 0.f;
    }
}

// ---------------------------------------------------------------------------
// K2: fused h_bar GEMM + per-column OMP — SINGLE-WAVE blocks (64 threads).
// Rationale (R1 post-mortem): the 4-wave block welded independent waves
// together through 9 __syncthreads; occupancy counter never moved when LDS
// shrank, so the limiter is lockstep structure, not static resources.
// Everything here is per-wave already. One wave per block:
//   - __syncthreads() becomes a trivial barrier (still emits the s_waitcnt
//     that fixes the re-stage WAR hazard — correctness logic unchanged),
//   - ~15 independent waves/CU (LDS 10.4KB/block, 128 VGPR) hide the per-k
//     serial chain (scan -> gk L2 load -> Cholesky -> solve -> update).
// Phase-1/phase-2 bodies are the proven R0 (73.7us) code, wave = 8 b.
// ---------------------------------------------------------------------------
__launch_bounds__(64, 4)
__global__ void k_omp(const float* __restrict__ data, const float* __restrict__ D,
                      const float* __restrict__ G, int* __restrict__ idx_out,
                      float* __restrict__ val_out) {
    const int lane = threadIdx.x;          // 0..63
    const int b0   = blockIdx.x * 8;       // this wave's 8 columns

    __shared__ __align__(16) float data_s[8][68];
    __shared__ __align__(16) float stage[2048];    // 8KB, 2-round re-stage

    // stage data tile (64 m x 8 b)
#pragma unroll
    for (int r = 0; r < 8; ++r) {
        int id = r * 64 + lane;
        int m = id >> 3, bb = id & 7;
        data_s[bb][m] = data[m * B_TOTAL + b0 + bb];
    }
    __syncthreads();

    const float4* __restrict__ D4 = (const float4*)D;
    const float4* __restrict__ G4 = (const float4*)G;

    // ---- phase 1: h_bar accumulators, 8 b x 8 atoms per lane ----
    float4 acc[8][2];
#pragma unroll
    for (int bb = 0; bb < 8; ++bb) {
        acc[bb][0] = make_float4(0.f, 0.f, 0.f, 0.f);
        acc[bb][1] = make_float4(0.f, 0.f, 0.f, 0.f);
    }

#pragma unroll 4
    for (int c = 0; c < 16; ++c) {
        float4 df[4][2];
#pragma unroll
        for (int mm = 0; mm < 4; ++mm) {
            df[mm][0] = D4[(c * 4 + mm) * 128 + lane];
            df[mm][1] = D4[(c * 4 + mm) * 128 + 64 + lane];
        }
#pragma unroll
        for (int bb = 0; bb < 8; ++bb) {
            const float4 dv = *(const float4*)&data_s[bb][c * 4];
            const float dm[4] = {dv.x, dv.y, dv.z, dv.w};
#pragma unroll
            for (int mm = 0; mm < 4; ++mm) {
                acc[bb][0].x = fmaf(df[mm][0].x, dm[mm], acc[bb][0].x);
                acc[bb][0].y = fmaf(df[mm][0].y, dm[mm], acc[bb][0].y);
                acc[bb][0].z = fmaf(df[mm][0].z, dm[mm], acc[bb][0].z);
                acc[bb][0].w = fmaf(df[mm][0].w, dm[mm], acc[bb][0].w);
                acc[bb][1].x = fmaf(df[mm][1].x, dm[mm], acc[bb][1].x);
                acc[bb][1].y = fmaf(df[mm][1].y, dm[mm], acc[bb][1].y);
                acc[bb][1].z = fmaf(df[mm][1].z, dm[mm], acc[bb][1].z);
                acc[bb][1].w = fmaf(df[mm][1].w, dm[mm], acc[bb][1].w);
            }
        }
    }

    // ---- re-stage: acc(8b x 8 atoms) -> hb(64 atoms of group's b) ----
    // 2 rounds of 4 b through the 8KB stage (R0 scheme, verbatim).
    const int g = lane >> 3;       // group = b within wave's 8
    const int p = lane & 7;        // lane within group
    float hb[64];
#pragma unroll
    for (int r = 0; r < 2; ++r) {
        __syncthreads();           // round r-1 reads complete before overwrite
#pragma unroll
        for (int q2 = 0; q2 < 4; ++q2) {
            int bb = r * 4 + q2;
            *(float4*)&stage[q2 * 512 + 4 * lane]       = acc[bb][0];
            *(float4*)&stage[q2 * 512 + 256 + 4 * lane] = acc[bb][1];
        }
        __syncthreads();           // writes committed before reads
        if ((g >> 2) == r) {
#pragma unroll
            for (int q = 0; q < 16; ++q) {
                const float4 v =
                    *(const float4*)&stage[(g & 3) * 512 + 32 * q + 4 * p];
                hb[4 * q + 0] = v.x;
                hb[4 * q + 1] = v.y;
                hb[4 * q + 2] = v.z;
                hb[4 * q + 3] = v.w;
            }
        }
    }

    // ---- phase 2: OMP, 8 concurrent b (one per 8-lane group) — R0 body ----
    float key[64];
#pragma unroll
    for (int e = 0; e < 64; ++e) key[e] = fabsf(hb[e]);

    unsigned msk0 = 0u, msk1 = 0u;
    int   I[KS];
    float xs[KS];
    float gsel[KS];
    float Lm[15];                   // packed lower-tri

#pragma unroll
    for (int k = 0; k < KS; ++k) {
        // --- local argmax over 64 register keys (mask pre-folded as -1) ---
        float bv = key[0]; int be = 0; float bhb = hb[0];
#pragma unroll
        for (int e = 1; e < 64; ++e) {
            bool gt = key[e] > bv;          // strict > keeps lowest e (n asc.)
            bv  = gt ? key[e] : bv;
            be  = gt ? e      : be;
            bhb = gt ? hb[e]  : bhb;
        }
        int bn = 32 * (be >> 2) + 4 * p + (be & 3);
        // --- 3-step reduce across the 8-lane group ---
#pragma unroll
        for (int off = 1; off < 8; off <<= 1) {
            float ov  = __shfl_xor(bv, off);
            int   on  = __shfl_xor(bn, off);
            float ohb = __shfl_xor(bhb, off);
            bool take = (ov > bv) || (ov == bv && on < bn);
            bv = take ? ov : bv; bn = take ? on : bn; bhb = take ? ohb : bhb;
        }
        const int nsel = bn;                // group-uniform
        I[k]    = nsel;
        gsel[k] = bhb;                      // = h_bar[nsel] (original), exact

        // mask the selected atom for future scans
        {
            int own  = (nsel >> 2) & 7;
            int esel = ((nsel >> 5) << 2) | (nsel & 3);
            if (p == own) {
                if (esel < 32) msk0 |= 1u << esel;
                else           msk1 |= 1u << (esel - 32);
            }
        }

        // --- Cholesky update of L ---
        if (k > 0) {
            float gk[KS - 1], w[KS - 1];
#pragma unroll
            for (int ti = 0; ti < KS - 1; ++ti)
                if (ti < k) gk[ti] = G[I[ti] * NATOM + nsel];
#pragma unroll
            for (int r = 0; r < KS - 1; ++r) {
                if (r < k) {
                    float s = gk[r];
#pragma unroll
                    for (int cc = 0; cc < KS - 1; ++cc)
                        if (cc < r) s -= Lm[r * (r + 1) / 2 + cc] * w[cc];
                    w[r] = s / Lm[r * (r + 1) / 2 + r];
                }
            }
            float s2 = 0.f;
#pragma unroll
            for (int r = 0; r < KS - 1; ++r) if (r < k) s2 += w[r] * w[r];
            float wc = sqrtf(fmaxf(0.f, 1.f - s2));
#pragma unroll
            for (int cc = 0; cc < KS - 1; ++cc)
                if (cc < k) Lm[k * (k + 1) / 2 + cc] = w[cc];
            Lm[k * (k + 1) / 2 + k] = wc;
        } else {
            Lm[0] = 1.f;
        }

        // --- solve L y = gsel ; L^T x = y (replicated within group) ---
        float y[KS];
#pragma unroll
        for (int r = 0; r <= k; ++r) {
            float s = gsel[r];
#pragma unroll
            for (int cc = 0; cc < r; ++cc) s -= Lm[r * (r + 1) / 2 + cc] * y[cc];
            y[r] = s / Lm[r * (r + 1) / 2 + r];
        }
#pragma unroll
        for (int r = k; r >= 0; --r) {
            float s = y[r];
#pragma unroll
            for (int cc = r + 1; cc <= k; ++cc) s -= Lm[cc * (cc + 1) / 2 + r] * xs[cc];
            xs[r] = s / Lm[r * (r + 1) / 2 + r];
        }

        // --- fused beta + key update (no beta[] array; ascending-ti fma) ---
        if (k < KS - 1) {
#pragma unroll
            for (int q = 0; q < 16; ++q) {
                float bx = 0.f, by = 0.f, bz = 0.f, bw = 0.f;
#pragma unroll
                for (int ti = 0; ti < KS - 1; ++ti) {
                    if (ti <= k) {
                        const float4 gc = G4[I[ti] * 128 + 8 * q + p];
                        bx = fmaf(xs[ti], gc.x, bx);
                        by = fmaf(xs[ti], gc.y, by);
                        bz = fmaf(xs[ti], gc.z, bz);
                        bw = fmaf(xs[ti], gc.w, bw);
                    }
                }
                {
                    float d0 = hb[4 * q + 0] - bx;
                    float d1 = hb[4 * q + 1] - by;
                    float d2 = hb[4 * q + 2] - bz;
                    float d3 = hb[4 * q + 3] - bw;
                    const int e0 = 4 * q;
                    bool m0 = (e0 + 0 < 32) ? ((msk0 >> (e0 + 0)) & 1u) : ((msk1 >> (e0 - 32)) & 1u);
                    bool m1 = (e0 + 1 < 32) ? ((msk0 >> (e0 + 1)) & 1u) : ((msk1 >> (e0 + 1 - 32)) & 1u);
                    bool m2 = (e0 + 2 < 32) ? ((msk0 >> (e0 + 2)) & 1u) : ((msk1 >> (e0 + 2 - 32)) & 1u);
                    bool m3 = (e0 + 3 < 32) ? ((msk0 >> (e0 + 3)) & 1u) : ((msk1 >> (e0 + 3 - 32)) & 1u);
                    key[e0 + 0] = m0 ? -1.f : fabsf(d0);
                    key[e0 + 1] = m1 ? -1.f : fabsf(d1);
                    key[e0 + 2] = m2 ? -1.f : fabsf(d2);
                    key[e0 + 3] = m3 ? -1.f : fabsf(d3);
                }
            }
        }
    }

    // direct outputs: one lane per b, consecutive addresses across g
    if (p == 0) {
#pragma unroll
        for (int k = 0; k < KS; ++k) {
            idx_out[k * B_TOTAL + b0 + g] = I[k];
            val_out[k * B_TOTAL + b0 + g] = xs[k];
        }
    }
}

// ---------------------------------------------------------------------------
// K_POST: fused coeff (blocks 0..1023) + recon (blocks 1024..1535).
// ---------------------------------------------------------------------------
__global__ void k_post(const int* __restrict__ idx, const float* __restrict__ val,
                       float* __restrict__ coeff, const float* __restrict__ dataT,
                       const float* __restrict__ D, float* __restrict__ zout,
                       float* __restrict__ acc) {
    __shared__ float lds[64][65];
    const int t = threadIdx.x;
    if (blockIdx.x < 1024) {
        const int bblk = blockIdx.x >> 3;
        const int jc   = blockIdx.x & 7;
        const int b    = bblk * 256 + t;
        int   I[KS]; float V[KS];
#pragma unroll
        for (int k = 0; k < KS; ++k) {
            I[k] = idx[k * B_TOTAL + b];
            V[k] = val[k * B_TOTAL + b];
        }
        const int j0 = jc * 64;
#pragma unroll 4
        for (int j = j0; j < j0 + 64; ++j) {
            float w = 0.f;
#pragma unroll
            for (int k = 0; k < KS; ++k) w = (I[k] == j) ? V[k] : w;
            coeff[j * B_TOTAL + b] = w;
        }
    } else {
        const int blk = blockIdx.x - 1024;
        const int n   = blk >> 4;
        const int hw0 = (blk & 15) * 64;
        float sq = 0.f;
#pragma unroll
        for (int r = 0; r < 16; ++r) {
            int id = r * 256 + t;
            int c = id & 63, j = id >> 6;
            int f = n * 65536 + (hw0 + j) * 64 + c;
            int b = f & 32767;
            int m = f >> 15;
            float zdl = 0.f;
#pragma unroll
            for (int k = 0; k < KS; ++k) {
                int   a = idx[k * B_TOTAL + b];
                float v = val[k * B_TOTAL + b];
                zdl = fmaf(v, D[m * NATOM + a], zdl);
            }
            float zp   = dataT[f];
            float diff = zdl - zp;
            lds[c][j] = zp + diff;
            sq = fmaf(diff, diff, sq);
        }
        __syncthreads();
#pragma unroll
        for (int r = 0; r < 16; ++r) {
            int id = r * 256 + t;
            int cc = id >> 6, i = id & 63;
            zout[n * 65536 + cc * 1024 + hw0 + i] = lds[cc][i];
        }
#pragma unroll
        for (int off = 32; off > 0; off >>= 1) sq += __shfl_xor(sq, off);
        __shared__ float red[4];
        if ((t & 63) == 0) red[t >> 6] = sq;
        __syncthreads();
        if (t == 0) atomicAdd(acc, red[0] + red[1] + red[2] + red[3]);
    }
}

// ---------------------------------------------------------------------------
// K4: finalize loss = 1.25 * mean(diff^2)
// ---------------------------------------------------------------------------
__global__ void k_loss(const float* __restrict__ acc, float* __restrict__ out_loss) {
    if (threadIdx.x == 0 && blockIdx.x == 0)
        *out_loss = 1.25f * (*acc / 2097152.f);
}

// ---------------------------------------------------------------------------
extern "C" void kernel_launch(void* const* d_in, const int* in_sizes, int n_in,
                              void* d_out, int out_size, void* d_ws, size_t ws_size,
                              hipStream_t stream) {
    const float* ze = (const float*)d_in[0];
    const float* D  = (const float*)d_in[1];

    float* G     = (float*)d_ws;
    int*   idxp  = (int*)  ((char*)d_ws + (size_t)262144 * 4);
    float* valp  = (float*)((char*)d_ws + (size_t)(262144 + 163840) * 4);
    float* accp  = (float*)((char*)d_ws + (size_t)(262144 + 2 * 163840) * 4);
    float* dataT = (float*)((char*)d_ws + (size_t)(262144 + 2 * 163840 + 64) * 4);

    float* zout  = (float*)d_out;
    float* lossp = zout + 2097152;
    float* coeff = zout + 2097153;

    k_prep<<<1024, 256, 0, stream>>>(ze, dataT, D, G, accp);
    k_omp <<<4096,  64, 0, stream>>>(dataT, D, G, idxp, valp);
    k_post<<<1536, 256, 0, stream>>>(idxp, valp, coeff, dataT, D, zout, accp);
    k_loss<<<1, 64, 0, stream>>>(accp, lossp);
}

// Round 3
// 179.899 us; speedup vs baseline: 2.1712x; 2.1712x over previous
//
#include <hip/hip_runtime.h>

#define B_TOTAL 32768
#define NATOM   512
#define MDIM    64
#define KS      5

// ---------------------------------------------------------------------------
// K_PREP: fused perm (blocks 0..511) + gram (blocks 512..1023).
// ---------------------------------------------------------------------------
__global__ void k_prep(const float* __restrict__ ze, float* __restrict__ dT,
                       const float* __restrict__ D, float* __restrict__ G,
                       float* __restrict__ acc) {
    __shared__ float lds[64][65];
    const int t = threadIdx.x;
    if (blockIdx.x < 512) {
        const int n   = blockIdx.x >> 4;
        const int hw0 = (blockIdx.x & 15) * 64;
#pragma unroll
        for (int r = 0; r < 16; ++r) {
            int id = r * 256 + t;
            int c = id >> 6, i = id & 63;
            lds[c][i] = ze[n * 65536 + c * 1024 + hw0 + i];
        }
        __syncthreads();
#pragma unroll
        for (int r = 0; r < 16; ++r) {
            int id = r * 256 + t;
            int c = id & 63, j = id >> 6;
            int hw = hw0 + j;
            int h = hw >> 5, w = hw & 31;
            int m = (n << 1) | (h >> 4);
            int b = ((h & 15) << 11) | (w << 6) | c;
            dT[m * 32768 + b] = lds[c][j];
        }
    } else {
        const int i = blockIdx.x - 512;
        float* col = &lds[0][0];
        if (t < MDIM) col[t] = D[t * NATOM + i];
        __syncthreads();
        for (int j = t; j < NATOM; j += 256) {
            float s = 0.f;
#pragma unroll
            for (int m = 0; m < MDIM; ++m) s = fmaf(col[m], D[m * NATOM + j], s);
            G[i * NATOM + j] = s;
        }
        if (i == 0 && t == 0) *acc = 0.f;
    }
}

// ---------------------------------------------------------------------------
// K2: fused h_bar GEMM + per-column OMP — single-wave blocks, register-lean.
// R2 post-mortem: __launch_bounds__(64,4) capped unified regs at ~128 (64
// arch VGPR) -> hb/key/acc spilled to scratch (FETCH 274MB, WRITE 323MB).
// Fix here:
//   (a) __launch_bounds__(64,2): cap 256, spill-impossible for ~110 live.
//   (b) R1's correctness-proven register-lean phase 2: ONE signed residual
//       h[64] (no hb+key pair, -64 VGPRs); fabs folds into compares as a
//       free src modifier; 4-chain ILP argmax; h updated incrementally via
//       solution delta dx (exact same G rows as the recompute version);
//       gsel[k] reconstructed from gk[] already loaded for Cholesky.
// Peak live set ~= phase-1 (acc[64]+df[32]) ~ 110 -> expect 128-160 VGPR
// -> 12-14 INDEPENDENT waves/CU (LDS 10.75KB caps at 14). The per-k serial
// chain (scan -> G L2 load -> Cholesky -> solve -> update) hides under them.
// ---------------------------------------------------------------------------
__launch_bounds__(64, 2)
__global__ void k_omp(const float* __restrict__ data, const float* __restrict__ D,
                      const float* __restrict__ G, int* __restrict__ idx_out,
                      float* __restrict__ val_out) {
    const int lane = threadIdx.x;          // 0..63
    const int b0   = blockIdx.x * 8;       // this wave's 8 columns

    __shared__ __align__(16) float data_s[8][68];
    __shared__ __align__(16) float stage[2048];    // 8KB, 2-round re-stage

    // stage data tile (64 m x 8 b)
#pragma unroll
    for (int r = 0; r < 8; ++r) {
        int id = r * 64 + lane;
        int m = id >> 3, bb = id & 7;
        data_s[bb][m] = data[m * B_TOTAL + b0 + bb];
    }
    __syncthreads();

    const float4* __restrict__ D4 = (const float4*)D;
    const float4* __restrict__ G4 = (const float4*)G;

    // ---- phase 1: h_bar accumulators, 8 b x 8 atoms per lane ----
    float4 acc[8][2];
#pragma unroll
    for (int bb = 0; bb < 8; ++bb) {
        acc[bb][0] = make_float4(0.f, 0.f, 0.f, 0.f);
        acc[bb][1] = make_float4(0.f, 0.f, 0.f, 0.f);
    }

#pragma unroll 4
    for (int c = 0; c < 16; ++c) {
        float4 df[4][2];
#pragma unroll
        for (int mm = 0; mm < 4; ++mm) {
            df[mm][0] = D4[(c * 4 + mm) * 128 + lane];
            df[mm][1] = D4[(c * 4 + mm) * 128 + 64 + lane];
        }
#pragma unroll
        for (int bb = 0; bb < 8; ++bb) {
            const float4 dv = *(const float4*)&data_s[bb][c * 4];
            const float dm[4] = {dv.x, dv.y, dv.z, dv.w};
#pragma unroll
            for (int mm = 0; mm < 4; ++mm) {
                acc[bb][0].x = fmaf(df[mm][0].x, dm[mm], acc[bb][0].x);
                acc[bb][0].y = fmaf(df[mm][0].y, dm[mm], acc[bb][0].y);
                acc[bb][0].z = fmaf(df[mm][0].z, dm[mm], acc[bb][0].z);
                acc[bb][0].w = fmaf(df[mm][0].w, dm[mm], acc[bb][0].w);
                acc[bb][1].x = fmaf(df[mm][1].x, dm[mm], acc[bb][1].x);
                acc[bb][1].y = fmaf(df[mm][1].y, dm[mm], acc[bb][1].y);
                acc[bb][1].z = fmaf(df[mm][1].z, dm[mm], acc[bb][1].z);
                acc[bb][1].w = fmaf(df[mm][1].w, dm[mm], acc[bb][1].w);
            }
        }
    }

    // ---- re-stage: acc(8b x 8 atoms) -> h(64 atoms of group's b) ----
    // 2 rounds of 4 b through the 8KB stage (R0 scheme, verbatim).
    const int g = lane >> 3;       // group = b within wave's 8
    const int p = lane & 7;        // lane within group
    float h[64];                   // current residual (starts as h_bar)
#pragma unroll
    for (int r = 0; r < 2; ++r) {
        __syncthreads();           // round r-1 reads complete before overwrite
#pragma unroll
        for (int q2 = 0; q2 < 4; ++q2) {
            int bb = r * 4 + q2;
            *(float4*)&stage[q2 * 512 + 4 * lane]       = acc[bb][0];
            *(float4*)&stage[q2 * 512 + 256 + 4 * lane] = acc[bb][1];
        }
        __syncthreads();           // writes committed before reads
        if ((g >> 2) == r) {
#pragma unroll
            for (int q = 0; q < 16; ++q) {
                const float4 v =
                    *(const float4*)&stage[(g & 3) * 512 + 32 * q + 4 * p];
                h[4 * q + 0] = v.x;
                h[4 * q + 1] = v.y;
                h[4 * q + 2] = v.z;
                h[4 * q + 3] = v.w;
            }
        }
    }

    // ---- phase 2: OMP, 8 concurrent b (one per 8-lane group) — R1 body ----
    unsigned msk0 = 0u, msk1 = 0u;
    int   I[KS];
    float xs[KS];
    float gsel[KS];
    float Lm[15];                   // packed lower-tri

#pragma unroll
    for (int k = 0; k < KS; ++k) {
        // --- 4-way ILP argmax over 64 register values (|h|, masked h==0) ---
        float cv[4]; int ce[4]; float ch[4];
#pragma unroll
        for (int c4 = 0; c4 < 4; ++c4) {
            cv[c4] = fabsf(h[16 * c4]); ce[c4] = 16 * c4; ch[c4] = h[16 * c4];
#pragma unroll
            for (int e = 16 * c4 + 1; e < 16 * c4 + 16; ++e) {
                float a = fabsf(h[e]);
                bool gt = a > cv[c4];       // strict > keeps lowest e
                cv[c4] = gt ? a    : cv[c4];
                ce[c4] = gt ? e    : ce[c4];
                ch[c4] = gt ? h[e] : ch[c4];
            }
        }
        // combine chains in ascending-e order; strict > keeps lower chain
        float bv = cv[0]; int be = ce[0]; float bh = ch[0];
#pragma unroll
        for (int c4 = 1; c4 < 4; ++c4) {
            bool gt = cv[c4] > bv;
            bv = gt ? cv[c4] : bv;
            be = gt ? ce[c4] : be;
            bh = gt ? ch[c4] : bh;
        }
        int bn = 32 * (be >> 2) + 4 * p + (be & 3);
        // --- 3-step reduce across the 8-lane group ---
#pragma unroll
        for (int off = 1; off < 8; off <<= 1) {
            float ov = __shfl_xor(bv, off);
            int   on = __shfl_xor(bn, off);
            float oh = __shfl_xor(bh, off);
            bool take = (ov > bv) || (ov == bv && on < bn);
            bv = take ? ov : bv; bn = take ? on : bn; bh = take ? oh : bh;
        }
        const int nsel = bn;                // group-uniform
        I[k] = nsel;

        // mask the selected atom for future scans
        {
            int own  = (nsel >> 2) & 7;
            int esel = ((nsel >> 5) << 2) | (nsel & 3);
            if (p == own) {
                if (esel < 32) msk0 |= 1u << esel;
                else           msk1 |= 1u << (esel - 32);
            }
        }

        // --- gsel reconstruction + Cholesky update of L ---
        if (k > 0) {
            float gk[KS - 1], w[KS - 1];
#pragma unroll
            for (int ti = 0; ti < KS - 1; ++ti)
                if (ti < k) gk[ti] = G[I[ti] * NATOM + nsel];
            // h_bar[nsel] = current residual + sum xs_old[ti]*G[I[ti],nsel]
            float hb_sel = bh;
#pragma unroll
            for (int ti = 0; ti < KS - 1; ++ti)
                if (ti < k) hb_sel = fmaf(xs[ti], gk[ti], hb_sel);
            gsel[k] = hb_sel;
#pragma unroll
            for (int r = 0; r < KS - 1; ++r) {
                if (r < k) {
                    float s = gk[r];
#pragma unroll
                    for (int cc = 0; cc < KS - 1; ++cc)
                        if (cc < r) s -= Lm[r * (r + 1) / 2 + cc] * w[cc];
                    w[r] = s / Lm[r * (r + 1) / 2 + r];
                }
            }
            float s2 = 0.f;
#pragma unroll
            for (int r = 0; r < KS - 1; ++r) if (r < k) s2 += w[r] * w[r];
            float wc = sqrtf(fmaxf(0.f, 1.f - s2));
#pragma unroll
            for (int cc = 0; cc < KS - 1; ++cc)
                if (cc < k) Lm[k * (k + 1) / 2 + cc] = w[cc];
            Lm[k * (k + 1) / 2 + k] = wc;
        } else {
            gsel[0] = bh;
            Lm[0] = 1.f;
        }

        // --- solve L y = gsel ; L^T x = y; record dx = x_new - x_old ---
        float y[KS];
#pragma unroll
        for (int r = 0; r <= k; ++r) {
            float s = gsel[r];
#pragma unroll
            for (int cc = 0; cc < r; ++cc) s -= Lm[r * (r + 1) / 2 + cc] * y[cc];
            y[r] = s / Lm[r * (r + 1) / 2 + r];
        }
        float dx[KS];
#pragma unroll
        for (int ti = 0; ti < KS; ++ti) dx[ti] = (ti < k) ? xs[ti] : 0.f;
#pragma unroll
        for (int r = k; r >= 0; --r) {
            float s = y[r];
#pragma unroll
            for (int cc = r + 1; cc <= k; ++cc) s -= Lm[cc * (cc + 1) / 2 + r] * xs[cc];
            xs[r] = s / Lm[r * (r + 1) / 2 + r];
        }
#pragma unroll
        for (int ti = 0; ti < KS; ++ti) if (ti <= k) dx[ti] = xs[ti] - dx[ti];

        // --- incremental residual update: h -= sum dx[ti]*G[I[ti]] ---
        if (k < KS - 1) {
#pragma unroll
            for (int q = 0; q < 16; ++q) {
                float bx = 0.f, by = 0.f, bz = 0.f, bw = 0.f;
#pragma unroll
                for (int ti = 0; ti < KS - 1; ++ti) {
                    if (ti <= k) {
                        const float4 gc = G4[I[ti] * 128 + 8 * q + p];
                        bx = fmaf(dx[ti], gc.x, bx);
                        by = fmaf(dx[ti], gc.y, by);
                        bz = fmaf(dx[ti], gc.z, bz);
                        bw = fmaf(dx[ti], gc.w, bw);
                    }
                }
                {
                    float d0 = h[4 * q + 0] - bx;
                    float d1 = h[4 * q + 1] - by;
                    float d2 = h[4 * q + 2] - bz;
                    float d3 = h[4 * q + 3] - bw;
                    const int e0 = 4 * q;
                    bool m0 = (e0 + 0 < 32) ? ((msk0 >> (e0 + 0)) & 1u) : ((msk1 >> (e0 - 32)) & 1u);
                    bool m1 = (e0 + 1 < 32) ? ((msk0 >> (e0 + 1)) & 1u) : ((msk1 >> (e0 + 1 - 32)) & 1u);
                    bool m2 = (e0 + 2 < 32) ? ((msk0 >> (e0 + 2)) & 1u) : ((msk1 >> (e0 + 2 - 32)) & 1u);
                    bool m3 = (e0 + 3 < 32) ? ((msk0 >> (e0 + 3)) & 1u) : ((msk1 >> (e0 + 3 - 32)) & 1u);
                    h[e0 + 0] = m0 ? 0.f : d0;
                    h[e0 + 1] = m1 ? 0.f : d1;
                    h[e0 + 2] = m2 ? 0.f : d2;
                    h[e0 + 3] = m3 ? 0.f : d3;
                }
            }
        }
    }

    // direct outputs: one lane per b, consecutive addresses across g
    if (p == 0) {
#pragma unroll
        for (int k = 0; k < KS; ++k) {
            idx_out[k * B_TOTAL + b0 + g] = I[k];
            val_out[k * B_TOTAL + b0 + g] = xs[k];
        }
    }
}

// ---------------------------------------------------------------------------
// K_POST: fused coeff (blocks 0..1023) + recon (blocks 1024..1535).
// ---------------------------------------------------------------------------
__global__ void k_post(const int* __restrict__ idx, const float* __restrict__ val,
                       float* __restrict__ coeff, const float* __restrict__ dataT,
                       const float* __restrict__ D, float* __restrict__ zout,
                       float* __restrict__ acc) {
    __shared__ float lds[64][65];
    const int t = threadIdx.x;
    if (blockIdx.x < 1024) {
        const int bblk = blockIdx.x >> 3;
        const int jc   = blockIdx.x & 7;
        const int b    = bblk * 256 + t;
        int   I[KS]; float V[KS];
#pragma unroll
        for (int k = 0; k < KS; ++k) {
            I[k] = idx[k * B_TOTAL + b];
            V[k] = val[k * B_TOTAL + b];
        }
        const int j0 = jc * 64;
#pragma unroll 4
        for (int j = j0; j < j0 + 64; ++j) {
            float w = 0.f;
#pragma unroll
            for (int k = 0; k < KS; ++k) w = (I[k] == j) ? V[k] : w;
            coeff[j * B_TOTAL + b] = w;
        }
    } else {
        const int blk = blockIdx.x - 1024;
        const int n   = blk >> 4;
        const int hw0 = (blk & 15) * 64;
        float sq = 0.f;
#pragma unroll
        for (int r = 0; r < 16; ++r) {
            int id = r * 256 + t;
            int c = id & 63, j = id >> 6;
            int f = n * 65536 + (hw0 + j) * 64 + c;
            int b = f & 32767;
            int m = f >> 15;
            float zdl = 0.f;
#pragma unroll
            for (int k = 0; k < KS; ++k) {
                int   a = idx[k * B_TOTAL + b];
                float v = val[k * B_TOTAL + b];
                zdl = fmaf(v, D[m * NATOM + a], zdl);
            }
            float zp   = dataT[f];
            float diff = zdl - zp;
            lds[c][j] = zp + diff;
            sq = fmaf(diff, diff, sq);
        }
        __syncthreads();
#pragma unroll
        for (int r = 0; r < 16; ++r) {
            int id = r * 256 + t;
            int cc = id >> 6, i = id & 63;
            zout[n * 65536 + cc * 1024 + hw0 + i] = lds[cc][i];
        }
#pragma unroll
        for (int off = 32; off > 0; off >>= 1) sq += __shfl_xor(sq, off);
        __shared__ float red[4];
        if ((t & 63) == 0) red[t >> 6] = sq;
        __syncthreads();
        if (t == 0) atomicAdd(acc, red[0] + red[1] + red[2] + red[3]);
    }
}

// ---------------------------------------------------------------------------
// K4: finalize loss = 1.25 * mean(diff^2)
// ---------------------------------------------------------------------------
__global__ void k_loss(const float* __restrict__ acc, float* __restrict__ out_loss) {
    if (threadIdx.x == 0 && blockIdx.x == 0)
        *out_loss = 1.25f * (*acc / 2097152.f);
}

// ---------------------------------------------------------------------------
extern "C" void kernel_launch(void* const* d_in, const int* in_sizes, int n_in,
                              void* d_out, int out_size, void* d_ws, size_t ws_size,
                              hipStream_t stream) {
    const float* ze = (const float*)d_in[0];
    const float* D  = (const float*)d_in[1];

    float* G     = (float*)d_ws;
    int*   idxp  = (int*)  ((char*)d_ws + (size_t)262144 * 4);
    float* valp  = (float*)((char*)d_ws + (size_t)(262144 + 163840) * 4);
    float* accp  = (float*)((char*)d_ws + (size_t)(262144 + 2 * 163840) * 4);
    float* dataT = (float*)((char*)d_ws + (size_t)(262144 + 2 * 163840 + 64) * 4);

    float* zout  = (float*)d_out;
    float* lossp = zout + 2097152;
    float* coeff = zout + 2097153;

    k_prep<<<1024, 256, 0, stream>>>(ze, dataT, D, G, accp);
    k_omp <<<4096,  64, 0, stream>>>(dataT, D, G, idxp, valp);
    k_post<<<1536, 256, 0, stream>>>(idxp, valp, coeff, dataT, D, zout, accp);
    k_loss<<<1, 64, 0, stream>>>(accp, lossp);
}